// Round 9
// baseline (2059.731 us; speedup 1.0000x reference)
//
#include <hip/hip_runtime.h>
#include <math.h>

#define NPTS 500000
#define TSIZE 524288u
#define TMASK (TSIZE - 1u)
#define CHUNKS 1954        // ceil(NPTS/256)
#define SLICE 245          // ceil(CHUNKS/8)
#define NBKT 32768         // 15-bit Morton buckets (32^3)
#define NBLK 128           // NBKT / 256

// ---- fused task-stream ranges (all constants, %8 alignment where needed) --
#define F_CNT_END  1954            // count tasks [0, 1954)
#define F_SCAN0    1960            // pad to 1960
#define F_SCAN_END 2088            // 128 scan tasks
#define F_SCAT0    2088
#define F_SCAT_END 4042            // 1954 scatter tasks
#define F_GATH0    4048            // pad; 4048 % 8 == 0 -> task xcd == block%8
#define F_GATH_END 35360           // 8 * (CHUNKS + 8*SLICE) = 31312 gather tasks
#define F_TRAN0    35360
#define F_END      43200           // 1960*4 transpose tasks (24 pads)

struct ResArgs { float r[16]; };

// ---- core per-(point,level) math: 6-request gather + trilinear blend -----
__device__ __forceinline__ float2 mhe_core(
    float x0, float x1, float x2,
    const float* __restrict__ tbl, int l, float res)
{
    float s0 = x0 * res, s1 = x1 * res, s2 = x2 * res;
    float f0 = floorf(s0), f1 = floorf(s1), f2 = floorf(s2);
    float w0 = s0 - f0, w1 = s1 - f1, w2 = s2 - f2;
    unsigned u0 = (unsigned)f0, u1 = (unsigned)f1, u2 = (unsigned)f2;

    unsigned b0 = u1 * 2654435761u, b1 = (u1 + 1u) * 2654435761u;
    unsigned c0 = u2 * 805459861u,  c1 = (u2 + 1u) * 805459861u;

    const float2* t  = (const float2*)tbl + (size_t)l * TSIZE;
    const float4* t4 = (const float4*)t;

    float v0a = 1.f - w0, v0b = w0;
    float v1a = 1.f - w1, v1b = w1;
    float v2a = 1.f - w2, v2b = w2;

    bool odd = (u0 & 1u) != 0u;
    unsigned u0p1 = u0 + 1u;

    float o0 = 0.f, o1 = 0.f;
#pragma unroll
    for (int j = 0; j < 4; ++j) {               // j bits: (j&1)=dy, (j&2)=dz
        unsigned bc = ((j & 1) ? b1 : b0) ^ ((j & 2) ? c1 : c0);
        unsigned e0 = (u0 ^ bc) & TMASK;
        float4 q = t4[e0 >> 1];                 // entries {e0&~1, e0|1}
        float2 lo = make_float2(q.x, q.y);
        float2 hi = make_float2(q.z, q.w);
        float2 fc0 = (e0 & 1u) ? hi : lo;
        float2 fc1 = (e0 & 1u) ? lo : hi;       // valid iff u0 even
        if (odd) {                              // predicated odd-lane fixup
            unsigned e1 = (u0p1 ^ bc) & TMASK;
            fc1 = t[e1];
        }
        float wyz = ((j & 1) ? v1b : v1a) * ((j & 2) ? v2b : v2a);
        o0 = fmaf(v0a * wyz, fc0.x, o0);
        o1 = fmaf(v0a * wyz, fc0.y, o1);
        o0 = fmaf(v0b * wyz, fc1.x, o0);
        o1 = fmaf(v0b * wyz, fc1.y, o1);
    }
    return make_float2(o0, o1);
}

// ---- Morton bucket -----------------------------------------------------
__device__ __forceinline__ unsigned mspread5(unsigned v) {
    return (v & 1u) | ((v & 2u) << 2) | ((v & 4u) << 4)
         | ((v & 8u) << 6) | ((v & 16u) << 8);
}
__device__ __forceinline__ unsigned bucket_of(float x0, float x1, float x2) {
    unsigned bx = (unsigned)min(31, (int)(x0 * 32.f));
    unsigned by = (unsigned)min(31, (int)(x1 * 32.f));
    unsigned bz = (unsigned)min(31, (int)(x2 * 32.f));
    return mspread5(bx) | (mspread5(by) << 1) | (mspread5(bz) << 2);
}

// ---- spin-wait (safe ONLY under cooperative launch: all blocks resident) --
__device__ __forceinline__ void wait_ge(const int* f, int tgt) {
    if (threadIdx.x == 0) {
        while (__hip_atomic_load(f, __ATOMIC_ACQUIRE,
                                 __HIP_MEMORY_SCOPE_AGENT) < tgt)
            __builtin_amdgcn_s_sleep(2);
    }
    __syncthreads();
}
__device__ __forceinline__ void signal_add(int* f) {
    __syncthreads();
    if (threadIdx.x == 0) { __threadfence(); atomicAdd(f, 1); }
}

// ============================================================================
// FUSED cooperative kernel: count -> scan -> scatter -> gather -> transpose
// as one grid-strided task stream with atomic dependency flags. Every wait
// targets a strictly earlier task class => deadlock-free given co-residency.
// ============================================================================
__global__ __launch_bounds__(256, 8) void mhe_fused(
    const float* __restrict__ x, const float* __restrict__ tbl,
    float2* __restrict__ out, float4* __restrict__ sx, int* __restrict__ perm,
    int* __restrict__ hist, int* __restrict__ ofs,
    int* __restrict__ chunkdone, int* __restrict__ cnt,
    float2* __restrict__ ws, ResArgs ra)
{
    __shared__ float2 tile[16][65];
    __shared__ int pidx[64];
    __shared__ int shs[256];
    const int tid = threadIdx.x;

    for (int t = blockIdx.x; t < F_END; t += gridDim.x) {
        if (t < F_CNT_END) {
            // ---- count: histogram of Morton buckets ----
            int p = t * 256 + tid;
            if (p < NPTS) {
                unsigned b = bucket_of(x[p * 3], x[p * 3 + 1], x[p * 3 + 2]);
                atomicAdd(&hist[b], 1);
            }
            signal_add(&cnt[0]);
        } else if (t < F_SCAN0) {
            // pad
        } else if (t < F_SCAN_END) {
            // ---- scan: ofs = exclusive prefix of hist ----
            wait_ge(&cnt[0], CHUNKS);
            int k = t - F_SCAN0;
            int acc = 0;
            for (int i = tid; i < k * 256; i += 256) acc += hist[i];
            shs[tid] = acc; __syncthreads();
            for (int o = 128; o > 0; o >>= 1) {
                if (tid < o) shs[tid] += shs[tid + o];
                __syncthreads();
            }
            int prefix = shs[0];
            __syncthreads();
            int v = hist[k * 256 + tid];
            shs[tid] = v; __syncthreads();
            for (int o = 1; o < 256; o <<= 1) {
                int u = (tid >= o) ? shs[tid - o] : 0;
                __syncthreads();
                shs[tid] += u;
                __syncthreads();
            }
            ofs[k * 256 + tid] = prefix + shs[tid] - v;
            signal_add(&cnt[1]);
        } else if (t < F_SCAT_END) {
            // ---- scatter: bucket-sorted points (sx) + permutation ----
            wait_ge(&cnt[1], NBLK);
            int p = (t - F_SCAT0) * 256 + tid;
            if (p < NPTS) {
                float x0 = x[p * 3], x1 = x[p * 3 + 1], x2 = x[p * 3 + 2];
                unsigned b = bucket_of(x0, x1, x2);
                int pos = atomicAdd(&ofs[b], 1);
                sx[pos] = make_float4(x0, x1, x2, 0.f);
                perm[pos] = p;
            }
            signal_add(&cnt[2]);
        } else if (t < F_GATH0) {
            // pad
        } else if (t < F_GATH_END) {
            // ---- gather: XCD-affine anchors (8..15) + chunk-major pool ----
            wait_ge(&cnt[2], CHUNKS);
            int g = t - F_GATH0;
            int xcd = g & 7;            // == physical block%8 (gridDim%8==0)
            int k = g >> 3;
            int l, chunk;
            if (k < CHUNKS) { l = 8 + xcd; chunk = k; }
            else { int j = k - CHUNKS; chunk = xcd * SLICE + (j >> 3); l = j & 7; }
            if (chunk < CHUNKS) {
                int p = chunk * 256 + tid;
                if (p < NPTS) {
                    float4 v = sx[p];
                    float2 o = mhe_core(v.x, v.y, v.z, tbl, l, ra.r[l]);
                    ws[(size_t)l * NPTS + p] = o;
                }
                signal_add(&chunkdone[chunk]);
            }
        } else {
            // ---- transpose+unpermute, ordered to chase the pool frontier ---
            int m = t - F_TRAN0;
            int idx = m >> 2, sub = m & 3;
            int chunk = (idx & 7) * SLICE + (idx >> 3);
            if (chunk >= CHUNKS) continue;
            wait_ge(&chunkdone[chunk], 16);
            int p0 = chunk * 256 + sub * 64;

            int pc = tid & 63;
#pragma unroll
            for (int i = 0; i < 4; ++i) {
                int l = (tid >> 6) + i * 4;
                int p = p0 + pc;
                if (p < NPTS) tile[l][pc] = ws[(size_t)l * NPTS + p];
            }
            if (tid < 64) {
                int p = p0 + tid;
                pidx[tid] = (p < NPTS) ? perm[p] : 0;
            }
            __syncthreads();
            float4* out4 = (float4*)out;
#pragma unroll
            for (int i = 0; i < 2; ++i) {
                int iq = tid + i * 256;
                int pt = iq >> 3, q = iq & 7;
                int p = p0 + pt;
                if (p < NPTS) {
                    int dp = pidx[pt];
                    float2 a = tile[2 * q][pt];
                    float2 b2 = tile[2 * q + 1][pt];
                    out4[(size_t)dp * 8 + q] = make_float4(a.x, a.y, b2.x, b2.y);
                }
            }
            __syncthreads();   // tile reused by this block's next task
        }
    }
}

// ============================================================================
// Fallback path (R7): separate kernels, used if cooperative launch unavailable
// ============================================================================
__global__ __launch_bounds__(256) void sort_count(
    const float* __restrict__ x, int* __restrict__ hist)
{
    int p = blockIdx.x * 256 + threadIdx.x;
    if (p >= NPTS) return;
    unsigned b = bucket_of(x[p * 3], x[p * 3 + 1], x[p * 3 + 2]);
    atomicAdd(&hist[b], 1);
}

__global__ __launch_bounds__(256) void scan_partial(
    const int* __restrict__ hist, int* __restrict__ bsum)
{
    __shared__ int s[256];
    int t = threadIdx.x;
    s[t] = hist[blockIdx.x * 256 + t];
    __syncthreads();
    for (int o = 128; o > 0; o >>= 1) {
        if (t < o) s[t] += s[t + o];
        __syncthreads();
    }
    if (t == 0) bsum[blockIdx.x] = s[0];
}

__global__ __launch_bounds__(256) void scan_final(
    const int* __restrict__ hist, const int* __restrict__ bsum,
    int* __restrict__ ofs)
{
    __shared__ int s[256];
    __shared__ int bp;
    int t = threadIdx.x;
    int v = hist[blockIdx.x * 256 + t];
    s[t] = v;
    if (t < 64) {
        int acc = 0;
        for (int i = t; i < (int)blockIdx.x; i += 64) acc += bsum[i];
#pragma unroll
        for (int o = 32; o > 0; o >>= 1) acc += __shfl_down(acc, o, 64);
        if (t == 0) bp = acc;
    }
    __syncthreads();
    for (int o = 1; o < 256; o <<= 1) {
        int u = (t >= o) ? s[t - o] : 0;
        __syncthreads();
        s[t] += u;
        __syncthreads();
    }
    ofs[blockIdx.x * 256 + t] = bp + s[t] - v;
}

__global__ __launch_bounds__(256) void sort_scatter(
    const float* __restrict__ x, int* __restrict__ ofs,
    float4* __restrict__ sx, int* __restrict__ perm)
{
    int p = blockIdx.x * 256 + threadIdx.x;
    if (p >= NPTS) return;
    float x0 = x[p * 3], x1 = x[p * 3 + 1], x2 = x[p * 3 + 2];
    unsigned b = bucket_of(x0, x1, x2);
    int pos = atomicAdd(&ofs[b], 1);
    sx[pos] = make_float4(x0, x1, x2, 0.f);
    perm[pos] = p;
}

template <bool SORTED>
__global__ __launch_bounds__(256) void mhe_gather(
    const float* __restrict__ x, const float4* __restrict__ sx,
    const float* __restrict__ tbl, float2* __restrict__ ws, ResArgs ra)
{
    int b = blockIdx.x;
    int xcd = b & 7;
    int t = b >> 3;
    int l, chunk;
    if (t < CHUNKS) { l = 8 + xcd; chunk = t; }
    else { int j = t - CHUNKS; chunk = xcd * SLICE + (j >> 3); l = j & 7;
           if (chunk >= CHUNKS) return; }
    int p = chunk * 256 + threadIdx.x;
    if (p >= NPTS) return;

    float x0, x1, x2;
    if (SORTED) { float4 v = sx[p]; x0 = v.x; x1 = v.y; x2 = v.z; }
    else        { x0 = x[p * 3]; x1 = x[p * 3 + 1]; x2 = x[p * 3 + 2]; }

    float2 o = mhe_core(x0, x1, x2, tbl, l, ra.r[l]);
    ws[(size_t)l * NPTS + p] = o;
}

template <bool PERM>
__global__ __launch_bounds__(256) void mhe_transpose(
    const float2* __restrict__ ws, const int* __restrict__ perm,
    float2* __restrict__ out)
{
    __shared__ float2 tile[16][65];
    __shared__ int pidx[64];
    int p0 = blockIdx.x * 64;
    int t = threadIdx.x;

    int pc = t & 63;
#pragma unroll
    for (int i = 0; i < 4; ++i) {
        int l = (t >> 6) + i * 4;
        int p = p0 + pc;
        if (p < NPTS) tile[l][pc] = ws[(size_t)l * NPTS + p];
    }
    if (PERM && t < 64) {
        int p = p0 + t;
        pidx[t] = (p < NPTS) ? perm[p] : 0;
    }
    __syncthreads();

    float4* out4 = (float4*)out;
#pragma unroll
    for (int i = 0; i < 2; ++i) {
        int idx = t + i * 256;
        int pt = idx >> 3, q = idx & 7;
        int p = p0 + pt;
        if (p >= NPTS) continue;
        int dp = PERM ? pidx[pt] : p;
        float2 a = tile[2 * q][pt];
        float2 b2 = tile[2 * q + 1][pt];
        out4[(size_t)dp * 8 + q] = make_float4(a.x, a.y, b2.x, b2.y);
    }
}

__global__ __launch_bounds__(256) void mhe_direct(
    const float* __restrict__ x, const float* __restrict__ tbl,
    float* __restrict__ out, ResArgs ra)
{
    int gid = blockIdx.x * 256 + threadIdx.x;
    int p = gid >> 4;
    int l = gid & 15;
    if (p >= NPTS) return;
    float2 o = mhe_core(x[p * 3], x[p * 3 + 1], x[p * 3 + 2], tbl, l, ra.r[l]);
    ((float2*)out)[(size_t)p * 16 + l] = o;
}

extern "C" void kernel_launch(void* const* d_in, const int* in_sizes, int n_in,
                              void* d_out, int out_size, void* d_ws, size_t ws_size,
                              hipStream_t stream) {
    const float* x   = (const float*)d_in[0];
    const float* tbl = (const float*)d_in[1];
    float2* out = (float2*)d_out;

    // RES computed on HOST with libm doubles (bit-exact vs numpy): levels
    // 3,6,9,12,15 land exactly on 32/64/128/256/512; device ulp flips floor().
    ResArgs ra;
    double bb = exp((log(512.0) - log(16.0)) / 15.0);
    for (int l = 0; l < 16; ++l)
        ra.r[l] = (float)floor(16.0 * pow(bb, (double)l));

    // ws carve-up (bytes)
    char* w = (char*)d_ws;
    float2* ws_lv = (float2*)w;                         // 64 MB
    float4* sx    = (float4*)(w + 64000000);            //  8 MB
    int*    perm  = (int*)(w + 72000000);               //  2 MB
    int*    hist  = (int*)(w + 74000000);               // 32768 ints
    int*    chunkdone = hist + NBKT;                    // 1954 ints
    int*    cnt   = chunkdone + CHUNKS;                 // 8 ints
    int*    ofs   = (int*)(w + 74000000 + 140000);      // 32768 ints
    int*    bsum  = ofs + NBKT;                         // 128 ints (fallback)
    const size_t ZERO_BYTES = (NBKT + CHUNKS + 8) * sizeof(int);
    const size_t WS_NEED = 74000000 + 140000 + (NBKT + NBLK) * sizeof(int);
    const size_t WS_T2 = (size_t)NPTS * 16 * sizeof(float2);

    int tasks_per_xcd = CHUNKS + 8 * SLICE;             // 3914
    int gather_grid = 8 * tasks_per_xcd;                // 31312
    int tp_grid = (NPTS + 63) / 64;                     // 7813

    if (ws_size >= WS_NEED) {
        // ---- try fused cooperative path ----
        bool coop_ok = false;
        int dev = 0, ncu = 0, coop = 0, occ = 0;
        hipGetDevice(&dev);
        hipDeviceGetAttribute(&ncu, hipDeviceAttributeMultiprocessorCount, dev);
        hipDeviceGetAttribute(&coop, hipDeviceAttributeCooperativeLaunch, dev);
        hipOccupancyMaxActiveBlocksPerMultiprocessor(&occ, mhe_fused, 256, 0);
        long long nb = (long long)occ * ncu;
        nb -= (nb & 7);                                  // keep task-xcd == b%8
        if (coop && nb >= 64) {
            hipMemsetAsync(hist, 0, ZERO_BYTES, stream);
            const float* xa = x; const float* ta = tbl; float2* oa = out;
            float4* sxa = sx; int* pa = perm; int* ha = hist; int* ofa = ofs;
            int* cda = chunkdone; int* cta = cnt; float2* wla = ws_lv;
            void* args[] = {(void*)&xa, (void*)&ta, (void*)&oa, (void*)&sxa,
                            (void*)&pa, (void*)&ha, (void*)&ofa, (void*)&cda,
                            (void*)&cta, (void*)&wla, (void*)&ra};
            hipError_t e = hipLaunchCooperativeKernel(
                reinterpret_cast<void*>(mhe_fused),
                dim3((unsigned)nb), dim3(256), args, 0, stream);
            coop_ok = (e == hipSuccess);
            if (!coop_ok) (void)hipGetLastError();
        }
        if (coop_ok) return;

        // ---- fallback: R7 multi-kernel path ----
        hipMemsetAsync(hist, 0, NBKT * sizeof(int), stream);
        sort_count<<<CHUNKS, 256, 0, stream>>>(x, hist);
        scan_partial<<<NBLK, 256, 0, stream>>>(hist, bsum);
        scan_final<<<NBLK, 256, 0, stream>>>(hist, bsum, ofs);
        sort_scatter<<<CHUNKS, 256, 0, stream>>>(x, ofs, sx, perm);
        mhe_gather<true><<<gather_grid, 256, 0, stream>>>(x, sx, tbl, ws_lv, ra);
        mhe_transpose<true><<<tp_grid, 256, 0, stream>>>(ws_lv, perm, out);
    } else if (ws_size >= WS_T2) {
        mhe_gather<false><<<gather_grid, 256, 0, stream>>>(x, nullptr, tbl,
                                                           ws_lv, ra);
        mhe_transpose<false><<<tp_grid, 256, 0, stream>>>(ws_lv, nullptr, out);
    } else {
        mhe_direct<<<(NPTS * 16 + 255) / 256, 256, 0, stream>>>(x, tbl,
                                                                (float*)out, ra);
    }
}

// Round 10
// 222.411 us; speedup vs baseline: 9.2609x; 9.2609x over previous
//
#include <hip/hip_runtime.h>
#include <math.h>

#define NPTS 500000
#define TSIZE 524288u
#define TMASK (TSIZE - 1u)
#define CHUNKS 1954        // ceil(NPTS/256)
#define SLICE 245          // ceil(CHUNKS/8)
#define NBKT 32768         // 15-bit Morton buckets (32^3)
#define NBLK 128           // NBKT / 256

struct ResArgs { float r[16]; };

// ---- core per-(point,level) math: 6-request gather + trilinear blend -----
// Request-rate model (validated R2..R7): time = per-XCD L2 line-requests /
// ~11.5 lines/cyc. 6 requests/point-level (4 float4 x-pairs + 2 avg odd-u0
// fixups) is the floor for this hash; fills are free, slots are the currency.
__device__ __forceinline__ float2 mhe_core(
    float x0, float x1, float x2,
    const float* __restrict__ tbl, int l, float res)
{
    float s0 = x0 * res, s1 = x1 * res, s2 = x2 * res;
    float f0 = floorf(s0), f1 = floorf(s1), f2 = floorf(s2);
    float w0 = s0 - f0, w1 = s1 - f1, w2 = s2 - f2;
    unsigned u0 = (unsigned)f0, u1 = (unsigned)f1, u2 = (unsigned)f2;

    unsigned b0 = u1 * 2654435761u, b1 = (u1 + 1u) * 2654435761u;
    unsigned c0 = u2 * 805459861u,  c1 = (u2 + 1u) * 805459861u;

    const float2* t  = (const float2*)tbl + (size_t)l * TSIZE;
    const float4* t4 = (const float4*)t;

    float v0a = 1.f - w0, v0b = w0;
    float v1a = 1.f - w1, v1b = w1;
    float v2a = 1.f - w2, v2b = w2;

    bool odd = (u0 & 1u) != 0u;
    unsigned u0p1 = u0 + 1u;

    float o0 = 0.f, o1 = 0.f;
#pragma unroll
    for (int j = 0; j < 4; ++j) {               // j bits: (j&1)=dy, (j&2)=dz
        unsigned bc = ((j & 1) ? b1 : b0) ^ ((j & 2) ? c1 : c0);
        unsigned e0 = (u0 ^ bc) & TMASK;
        float4 q = t4[e0 >> 1];                 // entries {e0&~1, e0|1}
        float2 lo = make_float2(q.x, q.y);
        float2 hi = make_float2(q.z, q.w);
        float2 fc0 = (e0 & 1u) ? hi : lo;
        float2 fc1 = (e0 & 1u) ? lo : hi;       // valid iff u0 even
        if (odd) {                              // predicated odd-lane fixup
            unsigned e1 = (u0p1 ^ bc) & TMASK;
            fc1 = t[e1];
        }
        float wyz = ((j & 1) ? v1b : v1a) * ((j & 2) ? v2b : v2a);
        o0 = fmaf(v0a * wyz, fc0.x, o0);
        o1 = fmaf(v0a * wyz, fc0.y, o1);
        o0 = fmaf(v0b * wyz, fc1.x, o0);
        o1 = fmaf(v0b * wyz, fc1.y, o1);
    }
    return make_float2(o0, o1);
}

// ---- Morton bucket (5 bits/dim interleaved, 32^3 buckets) ----------------
__device__ __forceinline__ unsigned mspread5(unsigned v) {
    return (v & 1u) | ((v & 2u) << 2) | ((v & 4u) << 4)
         | ((v & 8u) << 6) | ((v & 16u) << 8);
}
__device__ __forceinline__ unsigned bucket_of(float x0, float x1, float x2) {
    unsigned bx = (unsigned)min(31, (int)(x0 * 32.f));
    unsigned by = (unsigned)min(31, (int)(x1 * 32.f));
    unsigned bz = (unsigned)min(31, (int)(x2 * 32.f));
    return mspread5(bx) | (mspread5(by) << 1) | (mspread5(bz) << 2);
}

// ---- sort pipeline: histogram -> 2-kernel scan -> scatter ----------------
__global__ __launch_bounds__(256) void sort_count(
    const float* __restrict__ x, int* __restrict__ hist)
{
    int p = blockIdx.x * 256 + threadIdx.x;
    if (p >= NPTS) return;
    unsigned b = bucket_of(x[p * 3], x[p * 3 + 1], x[p * 3 + 2]);
    atomicAdd(&hist[b], 1);
}

__global__ __launch_bounds__(256) void scan_partial(
    const int* __restrict__ hist, int* __restrict__ bsum)
{
    __shared__ int s[256];
    int t = threadIdx.x;
    s[t] = hist[blockIdx.x * 256 + t];
    __syncthreads();
    for (int o = 128; o > 0; o >>= 1) {
        if (t < o) s[t] += s[t + o];
        __syncthreads();
    }
    if (t == 0) bsum[blockIdx.x] = s[0];
}

__global__ __launch_bounds__(256) void scan_final(
    const int* __restrict__ hist, const int* __restrict__ bsum,
    int* __restrict__ ofs)
{
    __shared__ int s[256];
    __shared__ int bp;
    int t = threadIdx.x;
    int v = hist[blockIdx.x * 256 + t];
    s[t] = v;
    if (t < 64) {
        int acc = 0;
        for (int i = t; i < (int)blockIdx.x; i += 64) acc += bsum[i];
#pragma unroll
        for (int o = 32; o > 0; o >>= 1) acc += __shfl_down(acc, o, 64);
        if (t == 0) bp = acc;
    }
    __syncthreads();
    for (int o = 1; o < 256; o <<= 1) {
        int u = (t >= o) ? s[t - o] : 0;
        __syncthreads();
        s[t] += u;
        __syncthreads();
    }
    ofs[blockIdx.x * 256 + t] = bp + s[t] - v;
}

__global__ __launch_bounds__(256) void sort_scatter(
    const float* __restrict__ x, int* __restrict__ ofs,
    float4* __restrict__ sx, int* __restrict__ perm)
{
    int p = blockIdx.x * 256 + threadIdx.x;
    if (p >= NPTS) return;
    float x0 = x[p * 3], x1 = x[p * 3 + 1], x2 = x[p * 3 + 2];
    unsigned b = bucket_of(x0, x1, x2);
    int pos = atomicAdd(&ofs[b], 1);
    sx[pos] = make_float4(x0, x1, x2, 0.f);
    perm[pos] = p;
}

// ---- gather: XCD-affine anchors (8..15) + chunk-major pool (0..7) --------
// blockIdx%8 -> XCD. Anchor level 8+xcd (4MB slice == the XCD's L2), then
// pooled coarse levels (L1-resident after Morton sort), chunk-major.
template <bool SORTED>
__global__ __launch_bounds__(256) void mhe_gather(
    const float* __restrict__ x, const float4* __restrict__ sx,
    const float* __restrict__ tbl, float2* __restrict__ ws, ResArgs ra)
{
    int b = blockIdx.x;
    int xcd = b & 7;
    int t = b >> 3;
    int l, chunk;
    if (t < CHUNKS) { l = 8 + xcd; chunk = t; }
    else { int j = t - CHUNKS; chunk = xcd * SLICE + (j >> 3); l = j & 7;
           if (chunk >= CHUNKS) return; }
    int p = chunk * 256 + threadIdx.x;
    if (p >= NPTS) return;

    float x0, x1, x2;
    if (SORTED) { float4 v = sx[p]; x0 = v.x; x1 = v.y; x2 = v.z; }
    else        { x0 = x[p * 3]; x1 = x[p * 3 + 1]; x2 = x[p * 3 + 2]; }

    float2 o = mhe_core(x0, x1, x2, tbl, l, ra.r[l]);
    ws[(size_t)l * NPTS + p] = o;   // coalesced (p = sorted position)
}

// ---- transpose + un-permute: ws[l][sp] -> out[perm[sp]][l] ---------------
// Each output point is one FULL 128B region (16 x float2): scattered
// per-point float4 writes are line-granular, same cost as coalesced.
template <bool PERM>
__global__ __launch_bounds__(256) void mhe_transpose(
    const float2* __restrict__ ws, const int* __restrict__ perm,
    float2* __restrict__ out)
{
    __shared__ float2 tile[16][65];
    __shared__ int pidx[64];
    int p0 = blockIdx.x * 64;
    int t = threadIdx.x;

    int pc = t & 63;
#pragma unroll
    for (int i = 0; i < 4; ++i) {
        int l = (t >> 6) + i * 4;
        int p = p0 + pc;
        if (p < NPTS) tile[l][pc] = ws[(size_t)l * NPTS + p];
    }
    if (PERM && t < 64) {
        int p = p0 + t;
        pidx[t] = (p < NPTS) ? perm[p] : 0;
    }
    __syncthreads();

    float4* out4 = (float4*)out;
#pragma unroll
    for (int i = 0; i < 2; ++i) {
        int idx = t + i * 256;
        int pt = idx >> 3, q = idx & 7;
        int p = p0 + pt;
        if (p >= NPTS) continue;
        int dp = PERM ? pidx[pt] : p;
        float2 a = tile[2 * q][pt];
        float2 b2 = tile[2 * q + 1][pt];
        out4[(size_t)dp * 8 + q] = make_float4(a.x, a.y, b2.x, b2.y);
    }
}

// ---- Fallback: direct-out single kernel (tiny ws) ------------------------
__global__ __launch_bounds__(256) void mhe_direct(
    const float* __restrict__ x, const float* __restrict__ tbl,
    float* __restrict__ out, ResArgs ra)
{
    int gid = blockIdx.x * 256 + threadIdx.x;
    int p = gid >> 4;
    int l = gid & 15;
    if (p >= NPTS) return;
    float2 o = mhe_core(x[p * 3], x[p * 3 + 1], x[p * 3 + 2], tbl, l, ra.r[l]);
    ((float2*)out)[(size_t)p * 16 + l] = o;
}

extern "C" void kernel_launch(void* const* d_in, const int* in_sizes, int n_in,
                              void* d_out, int out_size, void* d_ws, size_t ws_size,
                              hipStream_t stream) {
    const float* x   = (const float*)d_in[0];
    const float* tbl = (const float*)d_in[1];
    float2* out = (float2*)d_out;

    // RES computed on HOST with libm doubles (bit-exact vs numpy): levels
    // 3,6,9,12,15 land exactly on 32/64/128/256/512; device ulp flips floor().
    ResArgs ra;
    double bb = exp((log(512.0) - log(16.0)) / 15.0);
    for (int l = 0; l < 16; ++l)
        ra.r[l] = (float)floor(16.0 * pow(bb, (double)l));

    // ws carve-up (bytes)
    char* w = (char*)d_ws;
    float2* ws_lv = (float2*)w;                         // 64 MB
    float4* sx    = (float4*)(w + 64000000);            //  8 MB
    int*    perm  = (int*)(w + 72000000);               //  2 MB
    int*    hist  = (int*)(w + 74000000);               // 32768 ints
    int*    ofs   = (int*)(w + 74000000 + 140000);      // 32768 ints
    int*    bsum  = ofs + NBKT;                         // 128 ints
    const size_t WS_NEED = 74000000 + 140000 + (NBKT + NBLK) * sizeof(int);
    const size_t WS_T2 = (size_t)NPTS * 16 * sizeof(float2);

    int tasks_per_xcd = CHUNKS + 8 * SLICE;             // 3914
    int gather_grid = 8 * tasks_per_xcd;                // 31312
    int tp_grid = (NPTS + 63) / 64;                     // 7813

    if (ws_size >= WS_NEED) {
        hipMemsetAsync(hist, 0, NBKT * sizeof(int), stream);
        sort_count<<<CHUNKS, 256, 0, stream>>>(x, hist);
        scan_partial<<<NBLK, 256, 0, stream>>>(hist, bsum);
        scan_final<<<NBLK, 256, 0, stream>>>(hist, bsum, ofs);
        sort_scatter<<<CHUNKS, 256, 0, stream>>>(x, ofs, sx, perm);
        mhe_gather<true><<<gather_grid, 256, 0, stream>>>(x, sx, tbl, ws_lv, ra);
        mhe_transpose<true><<<tp_grid, 256, 0, stream>>>(ws_lv, perm, out);
    } else if (ws_size >= WS_T2) {
        mhe_gather<false><<<gather_grid, 256, 0, stream>>>(x, nullptr, tbl,
                                                           ws_lv, ra);
        mhe_transpose<false><<<tp_grid, 256, 0, stream>>>(ws_lv, nullptr, out);
    } else {
        mhe_direct<<<(NPTS * 16 + 255) / 256, 256, 0, stream>>>(x, tbl,
                                                                (float*)out, ra);
    }
}